// Round 1
// baseline (1232.966 us; speedup 1.0000x reference)
//
#include <hip/hip_runtime.h>
#include <math.h>

#define EMBED 1024
#define HEADS 16
#define HD 64
#define D3 (3 * EMBED)

// ---------------------------------------------------------------------------
// C[M,N] = A[M,K] @ W[N,K]^T + bias[N]
// 64x64 tile, BK=16, 256 threads, 4x4 micro-tile per thread, fp32.
// ---------------------------------------------------------------------------
__global__ __launch_bounds__(256) void gemm_bt_bias(
    const float* __restrict__ A, const float* __restrict__ W,
    const float* __restrict__ bias, float* __restrict__ C,
    int M, int N, int K)
{
    __shared__ float As[16][64 + 4];   // [k][m], pad 4 floats: 16B-aligned rows, <=2-way banks
    __shared__ float Bs[16][64 + 4];   // [k][n]

    const int t  = threadIdx.x;
    const int tn = t & 15;             // output col group
    const int tm = t >> 4;             // output row group
    const int bm = blockIdx.y * 64;
    const int bn = blockIdx.x * 64;

    const int lrow = t >> 2;           // 0..63 loader row
    const int lk   = (t & 3) * 4;      // 0,4,8,12 loader k offset

    float acc[4][4] = {};

    const float* Aptr = A + (size_t)(bm + lrow) * K + lk;
    const float* Wptr = W + (size_t)(bn + lrow) * K + lk;

    for (int k0 = 0; k0 < K; k0 += 16) {
        float4 av = *reinterpret_cast<const float4*>(Aptr + k0);
        float4 wv = *reinterpret_cast<const float4*>(Wptr + k0);
        As[lk + 0][lrow] = av.x; As[lk + 1][lrow] = av.y;
        As[lk + 2][lrow] = av.z; As[lk + 3][lrow] = av.w;
        Bs[lk + 0][lrow] = wv.x; Bs[lk + 1][lrow] = wv.y;
        Bs[lk + 2][lrow] = wv.z; Bs[lk + 3][lrow] = wv.w;
        __syncthreads();

#pragma unroll
        for (int kk = 0; kk < 16; ++kk) {
            float4 a = *reinterpret_cast<const float4*>(&As[kk][tm * 4]);
            float4 b = *reinterpret_cast<const float4*>(&Bs[kk][tn * 4]);
            float ar[4] = {a.x, a.y, a.z, a.w};
            float br[4] = {b.x, b.y, b.z, b.w};
#pragma unroll
            for (int i = 0; i < 4; ++i)
#pragma unroll
                for (int j = 0; j < 4; ++j)
                    acc[i][j] = fmaf(ar[i], br[j], acc[i][j]);
        }
        __syncthreads();
    }

#pragma unroll
    for (int i = 0; i < 4; ++i) {
        float4 o;
        o.x = acc[i][0] + bias[bn + tn * 4 + 0];
        o.y = acc[i][1] + bias[bn + tn * 4 + 1];
        o.z = acc[i][2] + bias[bn + tn * 4 + 2];
        o.w = acc[i][3] + bias[bn + tn * 4 + 3];
        *reinterpret_cast<float4*>(&C[(size_t)(bm + tm * 4 + i) * N + bn + tn * 4]) = o;
    }
}

// ---------------------------------------------------------------------------
// Flash attention forward, fp32. One block = one (b,h,q-tile of 64 rows).
// qkv layout: [B, S, 3*EMBED] with q at [0,1024), k at [1024,2048), v at [2048,3072).
// out layout: [B, S, EMBED].
// Thread (tm,tn): score rows tm*4+i, score cols tn+16*j (lane-consecutive K rows
// => 2-way LDS banks on ds_read_b128), output cols tn*4+j.
// ---------------------------------------------------------------------------
__global__ __launch_bounds__(256) void attn_fwd(
    const float* __restrict__ qkv, float* __restrict__ out, int S)
{
    const int qt = blockIdx.x;
    const int b  = blockIdx.y / HEADS;
    const int h  = blockIdx.y % HEADS;

    const float* Qb = qkv + (size_t)b * S * D3 + h * HD;
    const float* Kb = Qb + EMBED;
    const float* Vb = Qb + 2 * EMBED;

    __shared__ float Qs[64][HD + 4];
    __shared__ float Ks[64][HD + 4];
    __shared__ float Vs[64][HD + 4];
    __shared__ float Ps[64][64 + 4];

    const int t    = threadIdx.x;
    const int tn   = t & 15;
    const int tm   = t >> 4;
    const int lrow = t >> 2;
    const int lc   = (t & 3) * 4;

    // stage Q tile (rows qt*64 .. +63)
    {
        const float* src = Qb + (size_t)(qt * 64 + lrow) * D3 + lc;
#pragma unroll
        for (int c = 0; c < 4; ++c) {
            *reinterpret_cast<float4*>(&Qs[lrow][lc + c * 16]) =
                *reinterpret_cast<const float4*>(src + c * 16);
        }
    }

    float m[4], l[4], acc[4][4];
#pragma unroll
    for (int i = 0; i < 4; ++i) {
        m[i] = -1e30f; l[i] = 0.0f;
#pragma unroll
        for (int j = 0; j < 4; ++j) acc[i][j] = 0.0f;
    }

    const int nkt = S / 64;
    for (int kt = 0; kt < nkt; ++kt) {
        __syncthreads();   // prev PV done (also fences Q staging on first iter)

        // stage K,V tiles
        {
            const float* ksrc = Kb + (size_t)(kt * 64 + lrow) * D3 + lc;
            const float* vsrc = Vb + (size_t)(kt * 64 + lrow) * D3 + lc;
#pragma unroll
            for (int c = 0; c < 4; ++c) {
                *reinterpret_cast<float4*>(&Ks[lrow][lc + c * 16]) =
                    *reinterpret_cast<const float4*>(ksrc + c * 16);
                *reinterpret_cast<float4*>(&Vs[lrow][lc + c * 16]) =
                    *reinterpret_cast<const float4*>(vsrc + c * 16);
            }
        }
        __syncthreads();

        // scores: s[i][j] = sum_d Q[tm*4+i][d] * K[tn+16j][d]
        float s[4][4] = {};
#pragma unroll
        for (int d0 = 0; d0 < HD; d0 += 4) {
            float4 qa[4], kb[4];
#pragma unroll
            for (int i = 0; i < 4; ++i)
                qa[i] = *reinterpret_cast<const float4*>(&Qs[tm * 4 + i][d0]);
#pragma unroll
            for (int j = 0; j < 4; ++j)
                kb[j] = *reinterpret_cast<const float4*>(&Ks[tn + 16 * j][d0]);
#pragma unroll
            for (int i = 0; i < 4; ++i)
#pragma unroll
                for (int j = 0; j < 4; ++j) {
                    s[i][j] = fmaf(qa[i].x, kb[j].x, s[i][j]);
                    s[i][j] = fmaf(qa[i].y, kb[j].y, s[i][j]);
                    s[i][j] = fmaf(qa[i].z, kb[j].z, s[i][j]);
                    s[i][j] = fmaf(qa[i].w, kb[j].w, s[i][j]);
                }
        }

        // online softmax update (scale = 1/sqrt(64) = 0.125)
#pragma unroll
        for (int i = 0; i < 4; ++i) {
#pragma unroll
            for (int j = 0; j < 4; ++j) s[i][j] *= 0.125f;
            float rowmax = fmaxf(fmaxf(s[i][0], s[i][1]), fmaxf(s[i][2], s[i][3]));
#pragma unroll
            for (int off = 1; off < 16; off <<= 1)
                rowmax = fmaxf(rowmax, __shfl_xor(rowmax, off, 16));
            float mn   = fmaxf(m[i], rowmax);
            float corr = __expf(m[i] - mn);
            float rs   = 0.0f;
#pragma unroll
            for (int j = 0; j < 4; ++j) {
                s[i][j] = __expf(s[i][j] - mn);
                rs += s[i][j];
            }
#pragma unroll
            for (int off = 1; off < 16; off <<= 1)
                rs += __shfl_xor(rs, off, 16);
            l[i] = l[i] * corr + rs;
            m[i] = mn;
#pragma unroll
            for (int j = 0; j < 4; ++j) acc[i][j] *= corr;
#pragma unroll
            for (int j = 0; j < 4; ++j) Ps[tm * 4 + i][tn + 16 * j] = s[i][j];
        }
        __syncthreads();

        // PV: acc[i][j] += sum_c P[tm*4+i][c] * V[c][tn*4+j]
#pragma unroll
        for (int c0 = 0; c0 < 64; c0 += 4) {
            float4 pa[4];
            float  vbf[4][4];
#pragma unroll
            for (int i = 0; i < 4; ++i)
                pa[i] = *reinterpret_cast<const float4*>(&Ps[tm * 4 + i][c0]);
#pragma unroll
            for (int cc = 0; cc < 4; ++cc) {
                float4 tv = *reinterpret_cast<const float4*>(&Vs[c0 + cc][tn * 4]);
                vbf[cc][0] = tv.x; vbf[cc][1] = tv.y; vbf[cc][2] = tv.z; vbf[cc][3] = tv.w;
            }
#pragma unroll
            for (int i = 0; i < 4; ++i)
#pragma unroll
                for (int j = 0; j < 4; ++j) {
                    acc[i][j] = fmaf(pa[i].x, vbf[0][j], acc[i][j]);
                    acc[i][j] = fmaf(pa[i].y, vbf[1][j], acc[i][j]);
                    acc[i][j] = fmaf(pa[i].z, vbf[2][j], acc[i][j]);
                    acc[i][j] = fmaf(pa[i].w, vbf[3][j], acc[i][j]);
                }
        }
    }

    // epilogue: normalize by l and write to [B,S,EMBED]
#pragma unroll
    for (int i = 0; i < 4; ++i) {
        float inv = 1.0f / l[i];
        float4 o;
        o.x = acc[i][0] * inv;
        o.y = acc[i][1] * inv;
        o.z = acc[i][2] * inv;
        o.w = acc[i][3] * inv;
        *reinterpret_cast<float4*>(
            &out[(size_t)(b * S + qt * 64 + tm * 4 + i) * EMBED + h * HD + tn * 4]) = o;
    }
}

// ---------------------------------------------------------------------------
extern "C" void kernel_launch(void* const* d_in, const int* in_sizes, int n_in,
                              void* d_out, int out_size, void* d_ws, size_t ws_size,
                              hipStream_t stream)
{
    const float* x    = (const float*)d_in[0];  // [B,S,EMBED]
    const float* wqkv = (const float*)d_in[1];  // [3*EMBED, EMBED]
    const float* bqkv = (const float*)d_in[2];  // [3*EMBED]
    const float* wo   = (const float*)d_in[3];  // [EMBED, EMBED]
    const float* bo   = (const float*)d_in[4];  // [EMBED]
    float* out = (float*)d_out;                 // [B,S,EMBED]

    const int B = 2, S = 2048;
    const int M = B * S;                        // 4096

    float* qkv  = (float*)d_ws;                 // M * 3072 floats = 48 MiB
    float* attn = qkv + (size_t)M * D3;         // M * 1024 floats = 16 MiB

    // 1) fused QKV projection: qkv[M, 3072] = x @ wqkv^T + bqkv
    gemm_bt_bias<<<dim3(D3 / 64, M / 64), 256, 0, stream>>>(x, wqkv, bqkv, qkv,
                                                            M, D3, EMBED);
    // 2) attention
    attn_fwd<<<dim3(S / 64, B * HEADS), 256, 0, stream>>>(qkv, attn, S);
    // 3) output projection: out[M, 1024] = attn @ wo^T + bo
    gemm_bt_bias<<<dim3(EMBED / 64, M / 64), 256, 0, stream>>>(attn, wo, bo, out,
                                                               M, EMBED, EMBED);
}

// Round 3
// 275.227 us; speedup vs baseline: 4.4798x; 4.4798x over previous
//
#include <hip/hip_runtime.h>
#include <stdint.h>

#define EMBED 1024
#define HEADS 16
#define HD 64
#define D3 3072
#define SEQ 2048
#define MROWS 4096

typedef __attribute__((ext_vector_type(8))) short short8;
typedef __attribute__((ext_vector_type(4))) float f32x4;

static __device__ __forceinline__ ushort f2bf(float f) {
    uint32_t u = __builtin_bit_cast(uint32_t, f);
    uint32_t r = (u + 0x7fffu + ((u >> 16) & 1u)) >> 16;   // RNE
    return (ushort)r;
}

// async global->LDS, 16B per lane. LDS dest is wave-uniform base + lane*16 by HW;
// our chunk indexing (c = 256p + 64w + l -> byte c*16) matches that pattern.
static __device__ __forceinline__ void glds16(const void* g, void* l) {
    __builtin_amdgcn_global_load_lds(
        (const __attribute__((address_space(1))) uint32_t*)g,
        (__attribute__((address_space(3))) uint32_t*)(uintptr_t)l,
        16, 0, 0);
}

// ---------------------------------------------------------------------------
__global__ __launch_bounds__(256) void cvt_f32_bf16(const float* __restrict__ in,
                                                    ushort* __restrict__ out, int n4) {
    int i = blockIdx.x * 256 + threadIdx.x;
    if (i < n4) {
        float4 v = reinterpret_cast<const float4*>(in)[i];
        ushort4 o = { f2bf(v.x), f2bf(v.y), f2bf(v.z), f2bf(v.w) };
        reinterpret_cast<ushort4*>(out)[i] = o;
    }
}

// ---------------------------------------------------------------------------
// C[M,N] = A[M,K]@W[N,K]^T + bias. m97 structure: 128x128 tile, BK=32, 4 waves
// (2x2), each wave 4x4 frags of 16x16x32 bf16 MFMA. LDS seg-XOR swizzle with
// pre-swizzled global_load_lds source (involution: read seg g at phys g^(row&3)).
// ---------------------------------------------------------------------------
template<int OUT_BF16>
__global__ __launch_bounds__(256) void gemm_bt_mfma(
    const ushort* __restrict__ A, const ushort* __restrict__ W,
    const float* __restrict__ bias, void* __restrict__ Cout,
    int M, int N, int K)
{
    __shared__ __align__(16) ushort As[128 * 32];
    __shared__ __align__(16) ushort Bs[128 * 32];

    const int t = threadIdx.x;
    const int lane = t & 63;
    const int w = t >> 6;
    const int wm = w >> 1, wn = w & 1;
    const int bm = blockIdx.y * 128, bn = blockIdx.x * 128;
    const int r16 = lane & 15, g = lane >> 4;

    f32x4 acc[4][4];
#pragma unroll
    for (int i = 0; i < 4; ++i)
#pragma unroll
        for (int j = 0; j < 4; ++j) acc[i][j] = (f32x4){0.f, 0.f, 0.f, 0.f};

    for (int k0 = 0; k0 < K; k0 += 32) {
#pragma unroll
        for (int p = 0; p < 2; ++p) {
            int c = t + p * 256;
            int row = c >> 2;
            int sg = (c & 3) ^ (row & 3);
            glds16(A + (size_t)(bm + row) * K + k0 + sg * 8, (char*)As + c * 16);
            glds16(W + (size_t)(bn + row) * K + k0 + sg * 8, (char*)Bs + c * 16);
        }
        __syncthreads();

        short8 af[4], bf[4];
#pragma unroll
        for (int mt = 0; mt < 4; ++mt) {
            int row = wm * 64 + mt * 16 + r16;
            int off = (g * 16) ^ ((row & 3) << 4);
            af[mt] = *reinterpret_cast<const short8*>((const char*)As + row * 64 + off);
        }
#pragma unroll
        for (int nt = 0; nt < 4; ++nt) {
            int row = wn * 64 + nt * 16 + r16;
            int off = (g * 16) ^ ((row & 3) << 4);
            bf[nt] = *reinterpret_cast<const short8*>((const char*)Bs + row * 64 + off);
        }
#pragma unroll
        for (int mt = 0; mt < 4; ++mt)
#pragma unroll
            for (int nt = 0; nt < 4; ++nt)
                acc[mt][nt] = __builtin_amdgcn_mfma_f32_16x16x32_bf16(
                    af[mt], bf[nt], acc[mt][nt], 0, 0, 0);
        __syncthreads();
    }

    // epilogue: D row = (lane>>4)*4+reg, col = lane&15 (verified m89)
#pragma unroll
    for (int mt = 0; mt < 4; ++mt) {
#pragma unroll
        for (int nt = 0; nt < 4; ++nt) {
            int col = bn + wn * 64 + nt * 16 + r16;
            float bv = bias[col];
#pragma unroll
            for (int r = 0; r < 4; ++r) {
                size_t rowg = (size_t)(bm + wm * 64 + mt * 16 + g * 4 + r);
                float v = acc[mt][nt][r] + bv;
                if (OUT_BF16) ((ushort*)Cout)[rowg * N + col] = f2bf(v);
                else          ((float*)Cout)[rowg * N + col] = v;
            }
        }
    }
}

// ---------------------------------------------------------------------------
// Flash attention, bf16 MFMA. Block = 256 thr (4 waves) = 64 q rows (16/wave).
// KBLK=64. K staged via glds (pre-swz src), V transpose-staged (reg->LDS, kc-
// contiguous rows), P per-wave in LDS. fp32 online softmax on C-frags.
// All LDS tiles [64][128B] with off ^= ((row&7)<<4) swizzle.
// ---------------------------------------------------------------------------
__global__ __launch_bounds__(256) void attn_mfma(
    const ushort* __restrict__ qkv, ushort* __restrict__ outb)
{
    __shared__ __align__(16) ushort lds[12288];   // 24 KiB
    ushort* Ks = lds;            // [64][64] bf16, swizzled
    ushort* Vt = lds + 4096;     // [64 d][64 kc]
    ushort* Ps = lds + 8192;     // 4 x [16][64] per wave

    const int t = threadIdx.x, lane = t & 63, w = t >> 6;
    const int qt = blockIdx.x, bh = blockIdx.y;
    const int b = bh >> 4, h = bh & 15;
    const int r16 = lane & 15, g = lane >> 4;

    const ushort* Qb = qkv + (size_t)b * SEQ * D3 + h * HD;
    const ushort* Kb = Qb + EMBED;
    const ushort* Vb = Qb + 2 * EMBED;

    // Q fragments in registers: A[q=r16][d = 8g..8g+7 (+32*ks)]
    short8 qf[2];
    {
        const ushort* qrow = Qb + (size_t)(qt * 64 + w * 16 + r16) * D3 + g * 8;
#pragma unroll
        for (int ks = 0; ks < 2; ++ks)
            qf[ks] = *reinterpret_cast<const short8*>(qrow + ks * 32);
    }

    f32x4 o[4];
    float mreg[4], lreg[4];
#pragma unroll
    for (int dt = 0; dt < 4; ++dt) o[dt] = (f32x4){0.f, 0.f, 0.f, 0.f};
#pragma unroll
    for (int i = 0; i < 4; ++i) { mreg[i] = -1e30f; lreg[i] = 0.f; }

    for (int kt = 0; kt < SEQ / 64; ++kt) {
        __syncthreads();                       // prev PV reads done
        // stage K: 512 chunks of 16B, pre-swizzled source
#pragma unroll
        for (int p = 0; p < 2; ++p) {
            int c = t + p * 256;
            int row = c >> 3;
            int sg = (c & 7) ^ (row & 7);
            glds16(Kb + (size_t)(kt * 64 + row) * D3 + sg * 8, (char*)Ks + c * 16);
        }
        // stage V transposed: lane = kc row, wave*2+p = dseg
#pragma unroll
        for (int p = 0; p < 2; ++p) {
            int dseg = w * 2 + p;
            ushort vv[8];
            *reinterpret_cast<uint4*>(vv) =
                *reinterpret_cast<const uint4*>(Vb + (size_t)(kt * 64 + lane) * D3 + dseg * 8);
#pragma unroll
            for (int j = 0; j < 8; ++j) {
                int d = dseg * 8 + j;
                int off = (lane * 2) ^ ((d & 7) << 4);
                *(ushort*)((char*)Vt + d * 128 + off) = vv[j];
            }
        }
        __syncthreads();                       // staging visible

        // QK^T: scores[q][kc], frag ct covers kc = r16 + 16*ct
        f32x4 s[4];
#pragma unroll
        for (int ct = 0; ct < 4; ++ct) s[ct] = (f32x4){0.f, 0.f, 0.f, 0.f};
#pragma unroll
        for (int ct = 0; ct < 4; ++ct) {
#pragma unroll
            for (int ks = 0; ks < 2; ++ks) {
                int row = r16 + 16 * ct;
                int off = ((g + 4 * ks) * 16) ^ ((row & 7) << 4);
                short8 kf = *reinterpret_cast<const short8*>((const char*)Ks + row * 128 + off);
                s[ct] = __builtin_amdgcn_mfma_f32_16x16x32_bf16(qf[ks], kf, s[ct], 0, 0, 0);
            }
        }

        // online softmax (scale 1/sqrt(64)=0.125); lane's q-row (in-wave) = g*4+i
        ushort* Pw = Ps + w * 1024;
#pragma unroll
        for (int i = 0; i < 4; ++i) {
            float sv[4];
#pragma unroll
            for (int ct = 0; ct < 4; ++ct) sv[ct] = s[ct][i] * 0.125f;
            float sm = fmaxf(fmaxf(sv[0], sv[1]), fmaxf(sv[2], sv[3]));
#pragma unroll
            for (int m = 1; m < 16; m <<= 1) sm = fmaxf(sm, __shfl_xor(sm, m));
            float mn = fmaxf(mreg[i], sm);
            float corr = __expf(mreg[i] - mn);
            mreg[i] = mn;
            float rs = 0.f;
            int prow = g * 4 + i;
#pragma unroll
            for (int ct = 0; ct < 4; ++ct) {
                float p = __expf(sv[ct] - mn);
                rs += p;
                int kc = r16 + 16 * ct;
                int off = (kc * 2) ^ ((prow & 7) << 4);
                *(ushort*)((char*)Pw + prow * 128 + off) = f2bf(p);
            }
#pragma unroll
            for (int m = 1; m < 16; m <<= 1) rs += __shfl_xor(rs, m);
            lreg[i] = lreg[i] * corr + rs;
#pragma unroll
            for (int dt = 0; dt < 4; ++dt) o[dt][i] *= corr;
        }
        __syncthreads();                       // P visible (incl. own-wave lgkm drain)

        // PV: O[q][d] += P[q][kc] @ V[kc][d] ; A = P rows (q=r16), B = Vt rows (d)
        short8 pf[2];
#pragma unroll
        for (int ks = 0; ks < 2; ++ks) {
            int off = ((g + 4 * ks) * 16) ^ ((r16 & 7) << 4);
            pf[ks] = *reinterpret_cast<const short8*>((const char*)Pw + r16 * 128 + off);
        }
#pragma unroll
        for (int dt = 0; dt < 4; ++dt) {
#pragma unroll
            for (int ks = 0; ks < 2; ++ks) {
                int row = r16 + 16 * dt;
                int off = ((g + 4 * ks) * 16) ^ ((row & 7) << 4);
                short8 vf = *reinterpret_cast<const short8*>((const char*)Vt + row * 128 + off);
                o[dt] = __builtin_amdgcn_mfma_f32_16x16x32_bf16(pf[ks], vf, o[dt], 0, 0, 0);
            }
        }
    }

    // epilogue: q-row = g*4+i, d = r16 + 16*dt
    const size_t orow = (size_t)b * SEQ + qt * 64 + w * 16;
#pragma unroll
    for (int i = 0; i < 4; ++i) {
        float inv = 1.f / lreg[i];
#pragma unroll
        for (int dt = 0; dt < 4; ++dt)
            outb[(orow + g * 4 + i) * EMBED + h * HD + r16 + 16 * dt] = f2bf(o[dt][i] * inv);
    }
}

// ---------------------------------------------------------------------------
extern "C" void kernel_launch(void* const* d_in, const int* in_sizes, int n_in,
                              void* d_out, int out_size, void* d_ws, size_t ws_size,
                              hipStream_t stream)
{
    const float* x    = (const float*)d_in[0];
    const float* wqkv = (const float*)d_in[1];
    const float* bqkv = (const float*)d_in[2];
    const float* wo   = (const float*)d_in[3];
    const float* bo   = (const float*)d_in[4];
    float* out = (float*)d_out;

    ushort* xb    = (ushort*)d_ws;                       //  8 MiB
    ushort* wqkvb = xb + (size_t)MROWS * EMBED;          //  6 MiB
    ushort* wob   = wqkvb + (size_t)D3 * EMBED;          //  2 MiB
    ushort* qkvb  = wob + (size_t)EMBED * EMBED;         // 24 MiB
    ushort* attnb = qkvb + (size_t)MROWS * D3;           //  8 MiB

    cvt_f32_bf16<<<4096, 256, 0, stream>>>(x,    xb,    MROWS * EMBED / 4);
    cvt_f32_bf16<<<3072, 256, 0, stream>>>(wqkv, wqkvb, D3 * EMBED / 4);
    cvt_f32_bf16<<<1024, 256, 0, stream>>>(wo,   wob,   EMBED * EMBED / 4);

    gemm_bt_mfma<1><<<dim3(D3 / 128, MROWS / 128), 256, 0, stream>>>(
        xb, wqkvb, bqkv, qkvb, MROWS, D3, EMBED);

    attn_mfma<<<dim3(SEQ / 64, 2 * HEADS), 256, 0, stream>>>(qkvb, attnb);

    gemm_bt_mfma<0><<<dim3(EMBED / 128, MROWS / 128), 256, 0, stream>>>(
        attnb, wob, bo, out, MROWS, EMBED, EMBED);
}

// Round 4
// 234.850 us; speedup vs baseline: 5.2500x; 1.1719x over previous
//
#include <hip/hip_runtime.h>
#include <stdint.h>

#define EMBED 1024
#define HEADS 16
#define HD 64
#define D3 3072
#define SEQ 2048
#define MROWS 4096

typedef __attribute__((ext_vector_type(8))) short short8;
typedef __attribute__((ext_vector_type(4))) float f32x4;

static __device__ __forceinline__ ushort f2bf(float f) {
    uint32_t u = __builtin_bit_cast(uint32_t, f);
    uint32_t r = (u + 0x7fffu + ((u >> 16) & 1u)) >> 16;   // RNE
    return (ushort)r;
}

// async global->LDS, 16B per lane (wave-uniform dest base + lane*16).
static __device__ __forceinline__ void glds16(const void* g, void* l) {
    __builtin_amdgcn_global_load_lds(
        (const __attribute__((address_space(1))) uint32_t*)g,
        (__attribute__((address_space(3))) uint32_t*)(uintptr_t)l,
        16, 0, 0);
}

static __device__ __forceinline__ uint32_t cvt_pk_bf16(float lo, float hi) {
    uint32_t r;
    asm("v_cvt_pk_bf16_f32 %0, %1, %2" : "=v"(r) : "v"(lo), "v"(hi));
    return r;
}

// ---------------------------------------------------------------------------
__global__ __launch_bounds__(256) void cvt_f32_bf16(const float* __restrict__ in,
                                                    ushort* __restrict__ out, int n4) {
    int i = blockIdx.x * 256 + threadIdx.x;
    if (i < n4) {
        float4 v = reinterpret_cast<const float4*>(in)[i];
        ushort4 o = { f2bf(v.x), f2bf(v.y), f2bf(v.z), f2bf(v.w) };
        reinterpret_cast<ushort4*>(out)[i] = o;
    }
}

// ---------------------------------------------------------------------------
// C[M,N] = A[M,K]@W[N,K]^T + bias. 128x128 tile, BK=32, 4 waves (2x2),
// 16x16x32 bf16 MFMA, glds16 staging with pre-swizzled source.
// ---------------------------------------------------------------------------
template<int OUT_BF16>
__global__ __launch_bounds__(256) void gemm_bt_mfma(
    const ushort* __restrict__ A, const ushort* __restrict__ W,
    const float* __restrict__ bias, void* __restrict__ Cout,
    int M, int N, int K)
{
    __shared__ __align__(16) ushort As[128 * 32];
    __shared__ __align__(16) ushort Bs[128 * 32];

    const int t = threadIdx.x;
    const int lane = t & 63;
    const int w = t >> 6;
    const int wm = w >> 1, wn = w & 1;
    const int bm = blockIdx.y * 128, bn = blockIdx.x * 128;
    const int r16 = lane & 15, g = lane >> 4;

    f32x4 acc[4][4];
#pragma unroll
    for (int i = 0; i < 4; ++i)
#pragma unroll
        for (int j = 0; j < 4; ++j) acc[i][j] = (f32x4){0.f, 0.f, 0.f, 0.f};

    for (int k0 = 0; k0 < K; k0 += 32) {
#pragma unroll
        for (int p = 0; p < 2; ++p) {
            int c = t + p * 256;
            int row = c >> 2;
            int sg = (c & 3) ^ (row & 3);
            glds16(A + (size_t)(bm + row) * K + k0 + sg * 8, (char*)As + c * 16);
            glds16(W + (size_t)(bn + row) * K + k0 + sg * 8, (char*)Bs + c * 16);
        }
        __syncthreads();

        short8 af[4], bf[4];
#pragma unroll
        for (int mt = 0; mt < 4; ++mt) {
            int row = wm * 64 + mt * 16 + r16;
            int off = (g * 16) ^ ((row & 3) << 4);
            af[mt] = *reinterpret_cast<const short8*>((const char*)As + row * 64 + off);
        }
#pragma unroll
        for (int nt = 0; nt < 4; ++nt) {
            int row = wn * 64 + nt * 16 + r16;
            int off = (g * 16) ^ ((row & 3) << 4);
            bf[nt] = *reinterpret_cast<const short8*>((const char*)Bs + row * 64 + off);
        }
#pragma unroll
        for (int mt = 0; mt < 4; ++mt)
#pragma unroll
            for (int nt = 0; nt < 4; ++nt)
                acc[mt][nt] = __builtin_amdgcn_mfma_f32_16x16x32_bf16(
                    af[mt], bf[nt], acc[mt][nt], 0, 0, 0);
        __syncthreads();
    }

#pragma unroll
    for (int mt = 0; mt < 4; ++mt) {
#pragma unroll
        for (int nt = 0; nt < 4; ++nt) {
            int col = bn + wn * 64 + nt * 16 + r16;
            float bv = bias[col];
#pragma unroll
            for (int r = 0; r < 4; ++r) {
                size_t rowg = (size_t)(bm + wm * 64 + mt * 16 + g * 4 + r);
                float v = acc[mt][nt][r] + bv;
                if (OUT_BF16) ((ushort*)Cout)[rowg * N + col] = f2bf(v);
                else          ((float*)Cout)[rowg * N + col] = v;
            }
        }
    }
}

// ---------------------------------------------------------------------------
// Flash attention, bf16 MFMA, SWAPPED operands.
//   S^T = mfma(K, Q):  lane owns q-row (lane&15); scores at kc=16ct+4g+r.
//   O^T = mfma(Vt, P): lane holds O^T[d=16dt+4g+reg][q=lane&15].
// Softmax in exp2 domain, defer-max (THR=8), packed P writes (cvt_pk),
// double-buffered K/V (1 barrier/tile), V loads issued early (T14).
// ---------------------------------------------------------------------------
__global__ __launch_bounds__(256) void attn_mfma(
    const ushort* __restrict__ qkv, ushort* __restrict__ outb)
{
    __shared__ __align__(16) ushort lds[20480];   // 40 KiB: Ks[2] 16K, Vt[2] 16K, Ps 8K

    const int t = threadIdx.x, lane = t & 63, w = t >> 6;
    const int qt = blockIdx.x, bh = blockIdx.y;
    const int b = bh >> 4, h = bh & 15;
    const int r16 = lane & 15, g = lane >> 4;

    const ushort* Qb = qkv + (size_t)b * SEQ * D3 + h * HD;
    const ushort* Kb = Qb + EMBED;
    const ushort* Vb = Qb + 2 * EMBED;

    ushort* Pw = lds + 16384 + w * 1024;          // [16 q][64 kc], swizzled

    // Q fragments: lane holds Q[q=r16][d=8g..8g+7 (+32ks)] (B-operand layout)
    short8 qf[2];
    {
        const ushort* qrow = Qb + (size_t)(qt * 64 + w * 16 + r16) * D3 + g * 8;
#pragma unroll
        for (int ks = 0; ks < 2; ++ks)
            qf[ks] = *reinterpret_cast<const short8*>(qrow + ks * 32);
    }

    // staging helpers --------------------------------------------------------
    uint4 vv[2];
    auto stage_K = [&](int tile, ushort* dst) {
#pragma unroll
        for (int p = 0; p < 2; ++p) {
            int c = t + p * 256;
            int row = c >> 3;
            int sg = (c & 7) ^ (row & 7);
            glds16(Kb + (size_t)(tile * 64 + row) * D3 + sg * 8, (char*)dst + c * 16);
        }
    };
    auto load_V = [&](int tile) {
#pragma unroll
        for (int p = 0; p < 2; ++p) {
            int dseg = w * 2 + p;
            vv[p] = *reinterpret_cast<const uint4*>(
                Vb + (size_t)(tile * 64 + lane) * D3 + dseg * 8);
        }
    };
    auto write_V = [&](ushort* dst) {
#pragma unroll
        for (int p = 0; p < 2; ++p) {
            int dseg = w * 2 + p;
            ushort tmp[8];
            *reinterpret_cast<uint4*>(tmp) = vv[p];
#pragma unroll
            for (int j = 0; j < 8; ++j) {
                int d = dseg * 8 + j;
                int off = (lane * 2) ^ ((d & 7) << 4);
                *(ushort*)((char*)dst + d * 128 + off) = tmp[j];
            }
        }
    };

    f32x4 o[4];
#pragma unroll
    for (int dt = 0; dt < 4; ++dt) o[dt] = (f32x4){0.f, 0.f, 0.f, 0.f};
    float m2 = -1e30f, lsum = 0.f;

    const float SC = 0.18033688011112042f;        // 0.125 * log2(e)

    // prologue: stage tile 0
    stage_K(0, lds);
    load_V(0);
    write_V(lds + 8192);
    __syncthreads();

    const int NT = SEQ / 64;
    for (int kt = 0; kt < NT; ++kt) {
        const int cur = kt & 1;
        ushort* Kc = lds + cur * 4096;
        ushort* Vc = lds + 8192 + cur * 4096;
        ushort* Kn = lds + (cur ^ 1) * 4096;
        ushort* Vn = lds + 8192 + (cur ^ 1) * 4096;
        const bool more = (kt + 1 < NT);

        if (more) { stage_K(kt + 1, Kn); load_V(kt + 1); }

        // QK^T (swapped): s[ct] holds S^T rows kc=16ct+4g+reg, col q=r16
        f32x4 s[4];
#pragma unroll
        for (int ct = 0; ct < 4; ++ct) s[ct] = (f32x4){0.f, 0.f, 0.f, 0.f};
#pragma unroll
        for (int ct = 0; ct < 4; ++ct) {
#pragma unroll
            for (int ks = 0; ks < 2; ++ks) {
                int row = r16 + 16 * ct;
                int off = ((g + 4 * ks) * 16) ^ ((row & 7) << 4);
                short8 kf = *reinterpret_cast<const short8*>((const char*)Kc + row * 128 + off);
                s[ct] = __builtin_amdgcn_mfma_f32_16x16x32_bf16(kf, qf[ks], s[ct], 0, 0, 0);
            }
        }

        // softmax over lane's q-row (16 scores here; full row across 4 g-lanes)
        float sv[4][4];
        float pmax = -1e30f;
#pragma unroll
        for (int ct = 0; ct < 4; ++ct)
#pragma unroll
            for (int r = 0; r < 4; ++r) {
                sv[ct][r] = s[ct][r] * SC;
                pmax = fmaxf(pmax, sv[ct][r]);
            }
        pmax = fmaxf(pmax, __shfl_xor(pmax, 16));
        pmax = fmaxf(pmax, __shfl_xor(pmax, 32));

        if (!__all(pmax - m2 <= 8.0f)) {          // defer-max rescale
            float mn = fmaxf(m2, pmax);
            float corr = exp2f(m2 - mn);
            lsum *= corr;
#pragma unroll
            for (int dt = 0; dt < 4; ++dt)
#pragma unroll
                for (int r = 0; r < 4; ++r) o[dt][r] *= corr;
            m2 = mn;
        }

        float pv[4][4], rs = 0.f;
#pragma unroll
        for (int ct = 0; ct < 4; ++ct)
#pragma unroll
            for (int r = 0; r < 4; ++r) {
                pv[ct][r] = exp2f(sv[ct][r] - m2);
                rs += pv[ct][r];
            }
        rs += __shfl_xor(rs, 16);
        rs += __shfl_xor(rs, 32);
        lsum += rs;

        // packed P writes: kc = 16ct+4g+2j (+1 in high half)
#pragma unroll
        for (int ct = 0; ct < 4; ++ct)
#pragma unroll
            for (int j = 0; j < 2; ++j) {
                uint32_t pk = cvt_pk_bf16(pv[ct][2 * j], pv[ct][2 * j + 1]);
                int off = ((16 * ct + 4 * g + 2 * j) * 2) ^ ((r16 & 7) << 4);
                *(uint32_t*)((char*)Pw + r16 * 128 + off) = pk;
            }

        asm volatile("s_waitcnt lgkmcnt(0)" ::: "memory");   // own-wave P visible
        __builtin_amdgcn_sched_barrier(0);

        // PV (swapped): o[dt] = mfma(Vt rows d, P rows q)
        short8 pf[2];
#pragma unroll
        for (int ks = 0; ks < 2; ++ks) {
            int off = ((g + 4 * ks) * 16) ^ ((r16 & 7) << 4);
            pf[ks] = *reinterpret_cast<const short8*>((const char*)Pw + r16 * 128 + off);
        }
#pragma unroll
        for (int dt = 0; dt < 4; ++dt) {
#pragma unroll
            for (int ks = 0; ks < 2; ++ks) {
                int row = r16 + 16 * dt;
                int off = ((g + 4 * ks) * 16) ^ ((row & 7) << 4);
                short8 vf = *reinterpret_cast<const short8*>((const char*)Vc + row * 128 + off);
                o[dt] = __builtin_amdgcn_mfma_f32_16x16x32_bf16(vf, pf[ks], o[dt], 0, 0, 0);
            }
        }

        if (more) write_V(Vn);
        __syncthreads();     // drains glds (vmcnt) + V/P ds_writes; buffers flip
    }

    // epilogue: lane owns col q=r16; O^T rows d=16dt+4g+reg
    const size_t orow = (size_t)b * SEQ + qt * 64 + w * 16 + r16;
    float inv = 1.f / lsum;
#pragma unroll
    for (int dt = 0; dt < 4; ++dt) {
        ushort4 ov;
        ov.x = f2bf(o[dt][0] * inv);
        ov.y = f2bf(o[dt][1] * inv);
        ov.z = f2bf(o[dt][2] * inv);
        ov.w = f2bf(o[dt][3] * inv);
        *reinterpret_cast<ushort4*>(&outb[orow * EMBED + h * HD + dt * 16 + g * 4]) = ov;
    }
}

// ---------------------------------------------------------------------------
extern "C" void kernel_launch(void* const* d_in, const int* in_sizes, int n_in,
                              void* d_out, int out_size, void* d_ws, size_t ws_size,
                              hipStream_t stream)
{
    const float* x    = (const float*)d_in[0];
    const float* wqkv = (const float*)d_in[1];
    const float* bqkv = (const float*)d_in[2];
    const float* wo   = (const float*)d_in[3];
    const float* bo   = (const float*)d_in[4];
    float* out = (float*)d_out;

    ushort* xb    = (ushort*)d_ws;
    ushort* wqkvb = xb + (size_t)MROWS * EMBED;
    ushort* wob   = wqkvb + (size_t)D3 * EMBED;
    ushort* qkvb  = wob + (size_t)EMBED * EMBED;
    ushort* attnb = qkvb + (size_t)MROWS * D3;

    cvt_f32_bf16<<<4096, 256, 0, stream>>>(x,    xb,    MROWS * EMBED / 4);
    cvt_f32_bf16<<<3072, 256, 0, stream>>>(wqkv, wqkvb, D3 * EMBED / 4);
    cvt_f32_bf16<<<1024, 256, 0, stream>>>(wo,   wob,   EMBED * EMBED / 4);

    gemm_bt_mfma<1><<<dim3(D3 / 128, MROWS / 128), 256, 0, stream>>>(
        xb, wqkvb, bqkv, qkvb, MROWS, D3, EMBED);

    attn_mfma<<<dim3(SEQ / 64, 2 * HEADS), 256, 0, stream>>>(qkvb, attnb);

    gemm_bt_mfma<0><<<dim3(EMBED / 128, MROWS / 128), 256, 0, stream>>>(
        attnb, wob, bo, out, MROWS, EMBED, EMBED);
}

// Round 5
// 224.469 us; speedup vs baseline: 5.4928x; 1.0462x over previous
//
#include <hip/hip_runtime.h>
#include <stdint.h>

#define EMBED 1024
#define HEADS 16
#define HD 64
#define D3 3072
#define SEQ 2048
#define MROWS 4096

typedef __attribute__((ext_vector_type(8))) short short8;
typedef __attribute__((ext_vector_type(4))) float f32x4;
typedef __attribute__((ext_vector_type(16))) float f32x16;

static __device__ __forceinline__ ushort f2bf(float f) {
    uint32_t u = __builtin_bit_cast(uint32_t, f);
    uint32_t r = (u + 0x7fffu + ((u >> 16) & 1u)) >> 16;   // RNE
    return (ushort)r;
}

// async global->LDS, 16B per lane (wave-uniform dest base + lane*16).
static __device__ __forceinline__ void glds16(const void* g, void* l) {
    __builtin_amdgcn_global_load_lds(
        (const __attribute__((address_space(1))) uint32_t*)g,
        (__attribute__((address_space(3))) uint32_t*)(uintptr_t)l,
        16, 0, 0);
}

static __device__ __forceinline__ uint32_t cvt_pk_bf16(float lo, float hi) {
    uint32_t r;
    asm("v_cvt_pk_bf16_f32 %0, %1, %2" : "=v"(r) : "v"(lo), "v"(hi));
    return r;
}

// ---------------------------------------------------------------------------
__global__ __launch_bounds__(256) void cvt_f32_bf16(const float* __restrict__ in,
                                                    ushort* __restrict__ out, int n4) {
    int i = blockIdx.x * 256 + threadIdx.x;
    if (i < n4) {
        float4 v = reinterpret_cast<const float4*>(in)[i];
        ushort4 o = { f2bf(v.x), f2bf(v.y), f2bf(v.z), f2bf(v.w) };
        reinterpret_cast<ushort4*>(out)[i] = o;
    }
}

// ---------------------------------------------------------------------------
// C[M,N] = A[M,K]@W[N,K]^T + bias. 128x128 tile, BK=32, 4 waves (2x2),
// 16x16x32 bf16 MFMA, glds16 staging with pre-swizzled source. (unchanged)
// ---------------------------------------------------------------------------
template<int OUT_BF16>
__global__ __launch_bounds__(256) void gemm_bt_mfma(
    const ushort* __restrict__ A, const ushort* __restrict__ W,
    const float* __restrict__ bias, void* __restrict__ Cout,
    int M, int N, int K)
{
    __shared__ __align__(16) ushort As[128 * 32];
    __shared__ __align__(16) ushort Bs[128 * 32];

    const int t = threadIdx.x;
    const int lane = t & 63;
    const int w = t >> 6;
    const int wm = w >> 1, wn = w & 1;
    const int bm = blockIdx.y * 128, bn = blockIdx.x * 128;
    const int r16 = lane & 15, g = lane >> 4;

    f32x4 acc[4][4];
#pragma unroll
    for (int i = 0; i < 4; ++i)
#pragma unroll
        for (int j = 0; j < 4; ++j) acc[i][j] = (f32x4){0.f, 0.f, 0.f, 0.f};

    for (int k0 = 0; k0 < K; k0 += 32) {
#pragma unroll
        for (int p = 0; p < 2; ++p) {
            int c = t + p * 256;
            int row = c >> 2;
            int sg = (c & 3) ^ (row & 3);
            glds16(A + (size_t)(bm + row) * K + k0 + sg * 8, (char*)As + c * 16);
            glds16(W + (size_t)(bn + row) * K + k0 + sg * 8, (char*)Bs + c * 16);
        }
        __syncthreads();

        short8 af[4], bf[4];
#pragma unroll
        for (int mt = 0; mt < 4; ++mt) {
            int row = wm * 64 + mt * 16 + r16;
            int off = (g * 16) ^ ((row & 3) << 4);
            af[mt] = *reinterpret_cast<const short8*>((const char*)As + row * 64 + off);
        }
#pragma unroll
        for (int nt = 0; nt < 4; ++nt) {
            int row = wn * 64 + nt * 16 + r16;
            int off = (g * 16) ^ ((row & 3) << 4);
            bf[nt] = *reinterpret_cast<const short8*>((const char*)Bs + row * 64 + off);
        }
#pragma unroll
        for (int mt = 0; mt < 4; ++mt)
#pragma unroll
            for (int nt = 0; nt < 4; ++nt)
                acc[mt][nt] = __builtin_amdgcn_mfma_f32_16x16x32_bf16(
                    af[mt], bf[nt], acc[mt][nt], 0, 0, 0);
        __syncthreads();
    }

#pragma unroll
    for (int mt = 0; mt < 4; ++mt) {
#pragma unroll
        for (int nt = 0; nt < 4; ++nt) {
            int col = bn + wn * 64 + nt * 16 + r16;
            float bv = bias[col];
#pragma unroll
            for (int r = 0; r < 4; ++r) {
                size_t rowg = (size_t)(bm + wm * 64 + mt * 16 + g * 4 + r);
                float v = acc[mt][nt][r] + bv;
                if (OUT_BF16) ((ushort*)Cout)[rowg * N + col] = f2bf(v);
                else          ((float*)Cout)[rowg * N + col] = v;
            }
        }
    }
}

// ---------------------------------------------------------------------------
// Flash attention, 32x32x16 bf16 MFMA, swapped operands, QBLK=128 (4 waves x
// 32 q-rows), KVBLK=64.
//   S^T = mfma32(K, Q):  D col = q = lane&31; rows kc = (r&3)+8(r>>2)+4hi+32cb.
//   O^T = mfma32(Vt, P): D col = q; rows d likewise.
// A/B frag: row/col = lane&31, k = hi*8+j. Softmax exp2-domain, defer-max
// THR=8, cvt_pk packed P, dbuf K/V, 1 barrier/tile, setprio on MFMA clusters.
// LDS 48 KiB: K[2][64][64], Vt[2][64][64], P[4 waves][32 q][64 kc], all rows
// 128B with 16B-slot XOR swizzle key (row&7).
// ---------------------------------------------------------------------------
__global__ __launch_bounds__(256) void attn_mfma(
    const ushort* __restrict__ qkv, ushort* __restrict__ outb)
{
    __shared__ __align__(16) ushort lds[24576];   // 48 KiB

    const int t = threadIdx.x, lane = t & 63, w = t >> 6;
    const int qt = blockIdx.x, bh = blockIdx.y;
    const int b = bh >> 4, h = bh & 15;
    const int q31 = lane & 31, hi = lane >> 5;

    const ushort* Qb = qkv + (size_t)b * SEQ * D3 + h * HD;
    const ushort* Kb = Qb + EMBED;
    const ushort* Vb = Qb + 2 * EMBED;

    ushort* Pw = lds + 16384 + w * 2048;          // [32 q][64 kc] swizzled

    // Q fragments (B operand): col q=q31, k: d = 16ks + 8hi + j
    short8 qf[4];
    {
        const ushort* qrow = Qb + (size_t)(qt * 128 + w * 32 + q31) * D3 + 8 * hi;
#pragma unroll
        for (int ks = 0; ks < 4; ++ks)
            qf[ks] = *reinterpret_cast<const short8*>(qrow + ks * 16);
    }

    uint4 vv[2];
    auto stage_K = [&](int tile, ushort* dst) {
#pragma unroll
        for (int p = 0; p < 2; ++p) {
            int c = t + p * 256;
            int row = c >> 3;
            int sg = (c & 7) ^ (row & 7);
            glds16(Kb + (size_t)(tile * 64 + row) * D3 + sg * 8, (char*)dst + c * 16);
        }
    };
    auto load_V = [&](int tile) {
#pragma unroll
        for (int p = 0; p < 2; ++p) {
            int dseg = w * 2 + p;
            vv[p] = *reinterpret_cast<const uint4*>(
                Vb + (size_t)(tile * 64 + lane) * D3 + dseg * 8);
        }
    };
    auto write_V = [&](ushort* dst) {
#pragma unroll
        for (int p = 0; p < 2; ++p) {
            int dseg = w * 2 + p;
            ushort tmp[8];
            *reinterpret_cast<uint4*>(tmp) = vv[p];
#pragma unroll
            for (int j = 0; j < 8; ++j) {
                int d = dseg * 8 + j;
                int off = (lane * 2) ^ ((d & 7) << 4);
                *(ushort*)((char*)dst + d * 128 + off) = tmp[j];
            }
        }
    };

    f32x16 o[2];
#pragma unroll
    for (int db = 0; db < 2; ++db)
#pragma unroll
        for (int r = 0; r < 16; ++r) o[db][r] = 0.f;
    float m2 = -1e30f, lsum = 0.f;

    const float SC = 0.18033688011112042f;        // 0.125 * log2(e)

    stage_K(0, lds);
    load_V(0);
    write_V(lds + 8192);
    __syncthreads();

    const int NT = SEQ / 64;
    for (int kt = 0; kt < NT; ++kt) {
        const int cur = kt & 1;
        ushort* Kc = lds + cur * 4096;
        ushort* Vc = lds + 8192 + cur * 4096;
        ushort* Kn = lds + (cur ^ 1) * 4096;
        ushort* Vn = lds + 8192 + (cur ^ 1) * 4096;
        const bool more = (kt + 1 < NT);

        if (more) { stage_K(kt + 1, Kn); load_V(kt + 1); }

        // QK^T: s[cb] = S^T block rows kc=32cb.., cols q (accumulate over ks)
        f32x16 s[2];
#pragma unroll
        for (int cb = 0; cb < 2; ++cb)
#pragma unroll
            for (int r = 0; r < 16; ++r) s[cb][r] = 0.f;

        __builtin_amdgcn_s_setprio(1);
#pragma unroll
        for (int cb = 0; cb < 2; ++cb) {
            int row = cb * 32 + q31;
            int swz = (row & 7) << 4;
#pragma unroll
            for (int ks = 0; ks < 4; ++ks) {
                int off = (32 * ks + 16 * hi) ^ swz;
                short8 kf = *reinterpret_cast<const short8*>((const char*)Kc + row * 128 + off);
                s[cb] = __builtin_amdgcn_mfma_f32_32x32x16_bf16(kf, qf[ks], s[cb], 0, 0, 0);
            }
        }
        __builtin_amdgcn_s_setprio(0);

        // softmax over lane's q-row; partner lane^32 holds complementary kc
        float pmax = -1e30f;
#pragma unroll
        for (int cb = 0; cb < 2; ++cb)
#pragma unroll
            for (int r = 0; r < 16; ++r) {
                s[cb][r] *= SC;
                pmax = fmaxf(pmax, s[cb][r]);
            }
        pmax = fmaxf(pmax, __shfl_xor(pmax, 32));

        if (!__all(pmax - m2 <= 8.0f)) {          // defer-max rescale
            float mn = fmaxf(m2, pmax);
            float corr = exp2f(m2 - mn);
            lsum *= corr;
#pragma unroll
            for (int db = 0; db < 2; ++db)
#pragma unroll
                for (int r = 0; r < 16; ++r) o[db][r] *= corr;
            m2 = mn;
        }

        float rs = 0.f;
        int pswz = (q31 & 7) << 4;
#pragma unroll
        for (int cb = 0; cb < 2; ++cb)
#pragma unroll
            for (int r = 0; r < 16; r += 2) {
                float p0 = exp2f(s[cb][r] - m2);
                float p1 = exp2f(s[cb][r + 1] - m2);
                rs += p0 + p1;
                uint32_t pk = cvt_pk_bf16(p0, p1);
                int kc = 32 * cb + (r & 3) + 8 * (r >> 2) + 4 * hi;
                int off = (kc * 2) ^ pswz;
                *(uint32_t*)((char*)Pw + q31 * 128 + off) = pk;
            }
        rs += __shfl_xor(rs, 32);
        lsum += rs;

        asm volatile("s_waitcnt lgkmcnt(0)" ::: "memory");   // own-wave P visible
        __builtin_amdgcn_sched_barrier(0);

        // PV: o[db] += mfma32(Vt rows d, P rows kc -> cols q)
        short8 pB[4];
#pragma unroll
        for (int ks = 0; ks < 4; ++ks) {
            int off = (32 * ks + 16 * hi) ^ pswz;
            pB[ks] = *reinterpret_cast<const short8*>((const char*)Pw + q31 * 128 + off);
        }
        __builtin_amdgcn_s_setprio(1);
#pragma unroll
        for (int db = 0; db < 2; ++db) {
            int row = db * 32 + q31;
            int swz = (row & 7) << 4;
#pragma unroll
            for (int ks = 0; ks < 4; ++ks) {
                int off = (32 * ks + 16 * hi) ^ swz;
                short8 vf = *reinterpret_cast<const short8*>((const char*)Vc + row * 128 + off);
                o[db] = __builtin_amdgcn_mfma_f32_32x32x16_bf16(vf, pB[ks], o[db], 0, 0, 0);
            }
        }
        __builtin_amdgcn_s_setprio(0);

        if (more) write_V(Vn);
        __syncthreads();     // drains glds (vmcnt) + V ds_writes; buffers flip
    }

    // epilogue: lane owns q col q31; O^T rows d = (r&3)+8(r>>2)+4hi+32db
    const size_t orow = (size_t)b * SEQ + qt * 128 + w * 32 + q31;
    float inv = 1.f / lsum;
#pragma unroll
    for (int db = 0; db < 2; ++db) {
#pragma unroll
        for (int m = 0; m < 4; ++m) {
            int d0 = 32 * db + 8 * m + 4 * hi;
            ushort4 ov;
            ov.x = f2bf(o[db][4 * m + 0] * inv);
            ov.y = f2bf(o[db][4 * m + 1] * inv);
            ov.z = f2bf(o[db][4 * m + 2] * inv);
            ov.w = f2bf(o[db][4 * m + 3] * inv);
            *reinterpret_cast<ushort4*>(&outb[orow * EMBED + h * HD + d0]) = ov;
        }
    }
}

// ---------------------------------------------------------------------------
extern "C" void kernel_launch(void* const* d_in, const int* in_sizes, int n_in,
                              void* d_out, int out_size, void* d_ws, size_t ws_size,
                              hipStream_t stream)
{
    const float* x    = (const float*)d_in[0];
    const float* wqkv = (const float*)d_in[1];
    const float* bqkv = (const float*)d_in[2];
    const float* wo   = (const float*)d_in[3];
    const float* bo   = (const float*)d_in[4];
    float* out = (float*)d_out;

    ushort* xb    = (ushort*)d_ws;
    ushort* wqkvb = xb + (size_t)MROWS * EMBED;
    ushort* wob   = wqkvb + (size_t)D3 * EMBED;
    ushort* qkvb  = wob + (size_t)EMBED * EMBED;
    ushort* attnb = qkvb + (size_t)MROWS * D3;

    cvt_f32_bf16<<<4096, 256, 0, stream>>>(x,    xb,    MROWS * EMBED / 4);
    cvt_f32_bf16<<<3072, 256, 0, stream>>>(wqkv, wqkvb, D3 * EMBED / 4);
    cvt_f32_bf16<<<1024, 256, 0, stream>>>(wo,   wob,   EMBED * EMBED / 4);

    gemm_bt_mfma<1><<<dim3(D3 / 128, MROWS / 128), 256, 0, stream>>>(
        xb, wqkvb, bqkv, qkvb, MROWS, D3, EMBED);

    attn_mfma<<<dim3(SEQ / 128, 2 * HEADS), 256, 0, stream>>>(qkvb, attnb);

    gemm_bt_mfma<0><<<dim3(EMBED / 128, MROWS / 128), 256, 0, stream>>>(
        attnb, wob, bo, out, MROWS, EMBED, EMBED);
}